// Round 4
// baseline (494.294 us; speedup 1.0000x reference)
//
#include <hip/hip_runtime.h>
#include <math.h>

#define B 2
#define N 8192
#define M 8192
#define D 64
#define KNN 16
#define BM (B * M)           // 16384
#define GC 16                // grid cells per axis
#define NC (GC * GC * GC)    // 4096
#define NSC 64               // supercells (4x4x4)
#define WTMAX 192            // max wave-table entries per batch
#define CAP 48               // per-lane LDS candidate buffer slots

// Sorted-insert of (dd,ii) into per-lane top-16 (v ascending). Strict < keeps
// earlier-inserted on exact ties.
#define CHAIN_INSERT(DVAL, IVAL) do {                                   \
    float _dd = (DVAL); int _ii = (IVAL);                               \
    _Pragma("unroll")                                                   \
    for (int _r = 0; _r < KNN; ++_r) {                                  \
        bool  _sm = _dd < v[_r];                                        \
        float _tv = v[_r]; int _ti = id[_r];                            \
        v[_r]  = _sm ? _dd : _tv;  id[_r] = _sm ? _ii : _ti;            \
        _dd    = _sm ? _tv : _dd;  _ii    = _sm ? _ti : _ii;            \
    }                                                                   \
} while (0)

#define DRAIN() do {                                                    \
    int _mx = cnt;                                                      \
    _Pragma("unroll")                                                   \
    for (int _o = 32; _o; _o >>= 1)                                     \
        _mx = max(_mx, __shfl_xor(_mx, _o, 64));                        \
    _mx = __builtin_amdgcn_readfirstlane(_mx);                          \
    for (int _t = 0; _t < _mx; ++_t) {                                  \
        float _dv = fbuf[_t][lane];                                     \
        int _jj = ibuf[_t][lane];                                       \
        if (_t < cnt && _dv < v[KNN - 1]) CHAIN_INSERT(_dv, _jj);       \
    }                                                                   \
    cnt = 0; thr = v[KNN - 1];                                          \
} while (0)

// ---------------------------------------------------------------------------
// Kernel: histogram points into 4096 linear cells, queries into 64 supercells.
__global__ __launch_bounds__(256) void k_count(const float* __restrict__ xyz1,
                                               const float* __restrict__ xyz2,
                                               unsigned* __restrict__ pcount,
                                               unsigned* __restrict__ qcount) {
    int i = blockIdx.x * 256 + threadIdx.x;   // < B*N
    int b = i >> 13;
    const float* p = xyz1 + (size_t)i * 3;
    int cx = max(0, min(GC - 1, (int)(p[0] * GC)));
    int cy = max(0, min(GC - 1, (int)(p[1] * GC)));
    int cz = max(0, min(GC - 1, (int)(p[2] * GC)));
    atomicAdd(&pcount[b * NC + (cz * GC + cy) * GC + cx], 1u);
    const float* q = xyz2 + (size_t)i * 3;
    int qx = max(0, min(GC - 1, (int)(q[0] * GC)));
    int qy = max(0, min(GC - 1, (int)(q[1] * GC)));
    int qz = max(0, min(GC - 1, (int)(q[2] * GC)));
    int sc = ((qz >> 2) * 4 + (qy >> 2)) * 4 + (qx >> 2);
    atomicAdd(&qcount[b * NSC + sc], 1u);
}

// Kernel: blocks 0,1 = 4096-bin exclusive scan (points, per batch);
//         blocks 2,3 = 64-bin query scan + wave-table build (serial, tiny).
__global__ __launch_bounds__(256) void k_scan(const unsigned* __restrict__ pcount,
                                              const unsigned* __restrict__ qcount,
                                              unsigned* __restrict__ pstart,
                                              unsigned* __restrict__ pcur,
                                              unsigned* __restrict__ qcur,
                                              int* __restrict__ wtab,
                                              int* __restrict__ ntab) {
    __shared__ unsigned wsum[4];
    int blk = blockIdx.x;
    if (blk < 2) {
        int b = blk;
        int t = threadIdx.x;
        int base = b * NC + t * 16;
        unsigned c[16]; unsigned tsum = 0;
#pragma unroll
        for (int k = 0; k < 16; ++k) { c[k] = pcount[base + k]; tsum += c[k]; }
        int lane = t & 63, wv = t >> 6;
        unsigned x = tsum;
#pragma unroll
        for (int off = 1; off < 64; off <<= 1) {
            unsigned y = __shfl_up(x, off, 64);
            if (lane >= off) x += y;
        }
        if (lane == 63) wsum[wv] = x;
        __syncthreads();
        unsigned pre = 0;
        for (int k2 = 0; k2 < wv; ++k2) pre += wsum[k2];
        unsigned run = pre + x - tsum;
#pragma unroll
        for (int k = 0; k < 16; ++k) {
            pstart[base + k] = run; pcur[base + k] = run; run += c[k];
        }
    } else {
        int b = blk - 2;
        if (threadIdx.x != 0) return;
        int run = 0, nw = 0;
        for (int sc = 0; sc < NSC; ++sc) {
            int c = (int)qcount[b * NSC + sc];
            qcur[b * NSC + sc] = (unsigned)run;
            for (int o = 0; o < c; o += 64) {
                int num = min(64, c - o);
                wtab[b * WTMAX + nw++] = ((run + o) << 7) | num;
            }
            run += c;
        }
        ntab[b] = nw;
    }
}

// Kernel: scatter points (cell-sorted, with |p|^2) and queries (supercell-sorted).
__global__ __launch_bounds__(256) void k_scatter(const float* __restrict__ xyz1,
                                                 const float* __restrict__ xyz2,
                                                 unsigned* __restrict__ pcur,
                                                 unsigned* __restrict__ qcur,
                                                 float4* __restrict__ spts,
                                                 int* __restrict__ sidx,
                                                 float4* __restrict__ squery) {
    int i = blockIdx.x * 256 + threadIdx.x;   // < B*N
    int b = i >> 13;
    const float* p = xyz1 + (size_t)i * 3;
    float x = p[0], y = p[1], z = p[2];
    int cx = max(0, min(GC - 1, (int)(x * GC)));
    int cy = max(0, min(GC - 1, (int)(y * GC)));
    int cz = max(0, min(GC - 1, (int)(z * GC)));
    unsigned pos = atomicAdd(&pcur[b * NC + (cz * GC + cy) * GC + cx], 1u);
    spts[(size_t)b * N + pos] = make_float4(x, y, z, fmaf(x, x, fmaf(y, y, z * z)));
    sidx[(size_t)b * N + pos] = i & (N - 1);

    const float* q = xyz2 + (size_t)i * 3;
    float qx = q[0], qy = q[1], qz = q[2];
    int ax = max(0, min(GC - 1, (int)(qx * GC)));
    int ay = max(0, min(GC - 1, (int)(qy * GC)));
    int az = max(0, min(GC - 1, (int)(qz * GC)));
    int sc = ((az >> 2) * 4 + (ay >> 2)) * 4 + (ax >> 2);
    unsigned qpos = atomicAdd(&qcur[b * NSC + sc], 1u);
    squery[(size_t)b * M + qpos] = make_float4(qx, qy, qz, __int_as_float(i));
}

// Kernel: f = feature1 @ Wp + bp. Wave per row, lane = output channel.
__global__ __launch_bounds__(256) void k_proj(const float* __restrict__ feat,
                                              const float* __restrict__ Wp,
                                              const float* __restrict__ bp,
                                              float* __restrict__ f) {
    int c   = threadIdx.x & 63;
    int row = blockIdx.x * 4 + (threadIdx.x >> 6);   // 0..B*N-1
    const float* fr = feat + (size_t)row * 64;       // wave-uniform -> s_load
    float acc = bp[c];
#pragma unroll 8
    for (int d = 0; d < 64; ++d)
        acc = fmaf(fr[d], Wp[d * 64 + c], acc);
    f[(size_t)row * 64 + c] = acc;
}

// Kernel: exact grid KNN. One wave per <=64-query supercell group (wave-table).
// Expanding-box shells around the wave's cell bbox; wave-uniform x-row runs
// (scalar loads); per-lane threshold filter -> LDS buffer -> ring-end chain
// drains; per-lane exact stop bound vs box complement.
__global__ __launch_bounds__(64) void k_knn(const float4* __restrict__ spts,
                                            const int* __restrict__ sidx,
                                            const float4* __restrict__ squery,
                                            const unsigned* __restrict__ pstart,
                                            const unsigned* __restrict__ pcount,
                                            const int* __restrict__ wtab,
                                            const int* __restrict__ ntab,
                                            int* __restrict__ idx_out,
                                            float* __restrict__ w_out) {
    __shared__ unsigned short ibuf[CAP][64];   // 6 KB
    __shared__ float          fbuf[CAP][64];   // 12 KB
    int blk = blockIdx.x;
    int b = blk >= WTMAX ? 1 : 0;
    int ti = blk - b * WTMAX;
    if (ti >= ntab[b]) return;
    int e = wtab[b * WTMAX + ti];
    int qoff = e >> 7, qnum = e & 127;
    int lane = threadIdx.x;
    int sl = lane < qnum ? lane : qnum - 1;    // surplus lanes: dup last query
    float4 sq = squery[(size_t)b * M + qoff + sl];
    int gq = lane < qnum ? __float_as_int(sq.w) : -1;
    float qx = sq.x, qy = sq.y, qz = sq.z;
    float ax = -2.f * qx, ay = -2.f * qy, az = -2.f * qz;
    float q2 = fmaf(qx, qx, fmaf(qy, qy, qz * qz));

    int cx = max(0, min(GC - 1, (int)(qx * GC)));
    int cy = max(0, min(GC - 1, (int)(qy * GC)));
    int cz = max(0, min(GC - 1, (int)(qz * GC)));
    int mnx = cx, mxx = cx, mny = cy, mxy = cy, mnz = cz, mxz = cz;
#pragma unroll
    for (int off = 1; off < 64; off <<= 1) {
        mnx = min(mnx, __shfl_xor(mnx, off, 64));
        mxx = max(mxx, __shfl_xor(mxx, off, 64));
        mny = min(mny, __shfl_xor(mny, off, 64));
        mxy = max(mxy, __shfl_xor(mxy, off, 64));
        mnz = min(mnz, __shfl_xor(mnz, off, 64));
        mxz = max(mxz, __shfl_xor(mxz, off, 64));
    }
    mnx = __builtin_amdgcn_readfirstlane(mnx);
    mxx = __builtin_amdgcn_readfirstlane(mxx);
    mny = __builtin_amdgcn_readfirstlane(mny);
    mxy = __builtin_amdgcn_readfirstlane(mxy);
    mnz = __builtin_amdgcn_readfirstlane(mnz);
    mxz = __builtin_amdgcn_readfirstlane(mxz);

    float v[KNN]; int id[KNN];
#pragma unroll
    for (int r = 0; r < KNN; ++r) { v[r] = 3.4e38f; id[r] = 0; }
    float thr = 3.4e38f;
    int warm = 0, cnt = 0;
    int pb = b * N, cb = b * NC;
    int x0p = 0, x1p = -1, y0p = 0, y1p = -1, z0p = 0, z1p = -1;

    for (int r = 0; r < GC; ++r) {
        int x0 = max(mnx - r, 0), x1 = min(mxx + r, GC - 1);
        int y0 = max(mny - r, 0), y1 = min(mxy + r, GC - 1);
        int z0 = max(mnz - r, 0), z1 = min(mxz + r, GC - 1);
        int rowcnt = 0;
        for (int zz = z0; zz <= z1; ++zz)
        for (int yy = y0; yy <= y1; ++yy) {
            int a0 = x0, a1 = x1, c0 = 1, c1 = 0;           // run C empty
            if (zz >= z0p && zz <= z1p && yy >= y0p && yy <= y1p) {
                a1 = x0p - 1; c0 = x1p + 1; c1 = x1;        // exclude interior
            }
            for (int pass2 = 0; pass2 < 2; ++pass2) {
                int lo = pass2 ? c0 : a0, hi = pass2 ? c1 : a1;
                if (lo > hi) continue;
                int codeL = cb + (zz * GC + yy) * GC + lo;  // x-contiguous run
                int st = (int)pstart[codeL];
                int en = (int)pstart[codeL + (hi - lo)] + (int)pcount[codeL + (hi - lo)];
                st = __builtin_amdgcn_readfirstlane(st);
                en = __builtin_amdgcn_readfirstlane(en);
                for (int t = st; t < en; ++t) {
                    float4 p = spts[pb + t];                // s_load_dwordx4
                    float dv = fmaf(ax, p.x, p.w);
                    dv = fmaf(ay, p.y, dv);
                    dv = fmaf(az, p.z, dv);
                    if (warm < 16) {                        // wave-uniform
                        CHAIN_INSERT(dv, t);
                        if (++warm == 16) thr = v[KNN - 1];
                    } else if (cnt < CAP) {
                        ibuf[cnt][lane] = (unsigned short)t;
                        fbuf[cnt][lane] = dv;
                        cnt += dv < thr;
                    } else if (dv < thr) {                  // overflow (rare)
                        CHAIN_INSERT(dv, t);
                        thr = v[KNN - 1];
                    }
                }
            }
            ++rowcnt;
            if (r == 0 && rowcnt == 4) { DRAIN(); }         // fast thr warmup
        }
        DRAIN();
        // per-lane lower bound on d^2 of any point outside box(r)
        float lox = x0 * (1.f / GC), hix = (x1 + 1) * (1.f / GC);
        float loy = y0 * (1.f / GC), hiy = (y1 + 1) * (1.f / GC);
        float loz = z0 * (1.f / GC), hiz = (z1 + 1) * (1.f / GC);
        float bx = fminf(x0 > 0 ? qx - lox : 1e30f, x1 < GC - 1 ? hix - qx : 1e30f);
        float by = fminf(y0 > 0 ? qy - loy : 1e30f, y1 < GC - 1 ? hiy - qy : 1e30f);
        float bz = fminf(z0 > 0 ? qz - loz : 1e30f, z1 < GC - 1 ? hiz - qz : 1e30f);
        float lb = fminf(bx, fminf(by, bz));
        if (__all(v[KNN - 1] + q2 <= lb * lb * 0.99999f)) break;
        x0p = x0; x1p = x1; y0p = y0; y1p = y1; z0p = z0; z1p = z1;
    }

    if (gq >= 0) {
        w_out[gq] = (v[0] + q2 > 0.03f) ? 10.0f : 1.0f;
#pragma unroll
        for (int r2 = 0; r2 < KNN; ++r2)
            idx_out[(size_t)r2 * BM + gq] = sidx[pb + id[r2]];
    }
}

// Kernel: gather + MLP + reduce. One wave per query, lane = channel c.
__global__ __launch_bounds__(256) void k_final(const float* __restrict__ xyz1,
                                               const float* __restrict__ xyz2,
                                               const float* __restrict__ f,
                                               const int* __restrict__ idx,
                                               const float* __restrict__ W1,
                                               const float* __restrict__ b1,
                                               const float* __restrict__ W2,
                                               const float* __restrict__ b2,
                                               float* __restrict__ out) {
    __shared__ float w2s[64 * 64];      // 16 KB, [d][c]
    __shared__ float hT[4][64 * 16];    // 16 KB, per-wave [d][k]

    for (int t = threadIdx.x; t < 64 * 16; t += 256)
        ((float4*)w2s)[t] = ((const float4*)W2)[t];

    int wv = threadIdx.x >> 6;
    int c  = threadIdx.x & 63;
    int gq = blockIdx.x * 4 + wv;
    int b  = gq >> 13;

    const float* q = xyz2 + (size_t)gq * 3;
    float qx = q[0], qy = q[1], qz = q[2];
    float w10 = W1[c], w11 = W1[64 + c], w12 = W1[128 + c];
    float b1c = b1[c], b2c = b2[c];

    int nidx[KNN];
#pragma unroll
    for (int k = 0; k < KNN; ++k)
        nidx[k] = idx[(size_t)k * BM + gq];      // wave-broadcast load

    float h[KNN];
#pragma unroll
    for (int k = 0; k < KNN; ++k) {
        const float* p = xyz1 + ((size_t)b * N + nidx[k]) * 3;
        float gx = p[0] - qx, gy = p[1] - qy, gz = p[2] - qz;
        float t = fmaf(gx, w10, b1c);
        t = fmaf(gy, w11, t);
        t = fmaf(gz, w12, t);
        h[k] = fmaxf(t, 0.f);
    }

#pragma unroll
    for (int k = 0; k < KNN; k += 4)
        *(float4*)&hT[wv][c * 16 + k] = make_float4(h[k], h[k+1], h[k+2], h[k+3]);

    __syncthreads();   // covers W2 staging + hT visibility

    float y[KNN];
#pragma unroll
    for (int k = 0; k < KNN; ++k) y[k] = 0.f;

#pragma unroll 4
    for (int d = 0; d < 64; ++d) {
        float w2dc = w2s[d * 64 + c];                       // conflict-free
        const float4* hp = (const float4*)&hT[wv][d * 16];  // broadcast reads
        float hh[16];
        *(float4*)&hh[0]  = hp[0];
        *(float4*)&hh[4]  = hp[1];
        *(float4*)&hh[8]  = hp[2];
        *(float4*)&hh[12] = hp[3];
#pragma unroll
        for (int k = 0; k < KNN; ++k)
            y[k] = fmaf(hh[k], w2dc, y[k]);
    }

    float acc = 0.f;
#pragma unroll
    for (int k = 0; k < KNN; ++k) {
        float gfv = f[((size_t)b * N + nidx[k]) * 64 + c];  // coalesced row
        acc = fmaf(y[k] + b2c, gfv, acc);
    }
    out[(size_t)gq * 64 + c] = acc * 0.25f;   // 1/sqrt(16)
}

extern "C" void kernel_launch(void* const* d_in, const int* in_sizes, int n_in,
                              void* d_out, int out_size, void* d_ws, size_t ws_size,
                              hipStream_t stream) {
    const float* feature1 = (const float*)d_in[0];
    const float* xyz1     = (const float*)d_in[1];
    const float* xyz2     = (const float*)d_in[2];
    const float* Wp       = (const float*)d_in[3];
    const float* bp       = (const float*)d_in[4];
    const float* W1       = (const float*)d_in[5];
    const float* b1       = (const float*)d_in[6];
    const float* W2       = (const float*)d_in[7];
    const float* b2       = (const float*)d_in[8];
    float* out = (float*)d_out;

    char* w = (char*)d_ws;
    float4*   spts   = (float4*)w;    w += (size_t)B * N * 16;
    float4*   squery = (float4*)w;    w += (size_t)B * M * 16;
    float*    f      = (float*)w;     w += (size_t)B * N * D * 4;
    int*      sidx   = (int*)w;       w += (size_t)B * N * 4;
    unsigned* pcount = (unsigned*)w;  w += (size_t)B * NC * 4;
    unsigned* qcount = (unsigned*)w;  w += (size_t)B * NSC * 4;
    unsigned* pstart = (unsigned*)w;  w += (size_t)B * NC * 4;
    unsigned* pcur   = (unsigned*)w;  w += (size_t)B * NC * 4;
    unsigned* qcur   = (unsigned*)w;  w += (size_t)B * NSC * 4;
    int*      wtab   = (int*)w;       w += (size_t)B * WTMAX * 4;
    int*      ntab   = (int*)w;       w += 16;
    int*      idxf   = (int*)w;       w += (size_t)KNN * BM * 4;
    float*    w_out  = out + (size_t)BM * D;

    // zero the two histogram arrays (contiguous)
    hipMemsetAsync(pcount, 0, (size_t)(B * NC + B * NSC) * 4, stream);

    k_count<<<BM / 256, 256, 0, stream>>>(xyz1, xyz2, pcount, qcount);
    k_scan<<<4, 256, 0, stream>>>(pcount, qcount, pstart, pcur, qcur, wtab, ntab);
    k_scatter<<<BM / 256, 256, 0, stream>>>(xyz1, xyz2, pcur, qcur, spts, sidx, squery);
    k_proj<<<B * N / 4, 256, 0, stream>>>(feature1, Wp, bp, f);
    k_knn<<<2 * WTMAX, 64, 0, stream>>>(spts, sidx, squery, pstart, pcount,
                                        wtab, ntab, idxf, w_out);
    k_final<<<BM / 4, 256, 0, stream>>>(xyz1, xyz2, f, idxf, W1, b1, W2, b2, out);
}